// Round 12
// baseline (532.553 us; speedup 1.0000x reference)
//
#include <hip/hip_runtime.h>
#include <cstddef>
#include <cstdint>

#define NN 100000
#define NPAD 100032          // NN rounded to 64 (gemm row tiles)
#define NE 1600000
#define ET (NE + NN)
#define ETP_MAX (ET + 8 * NN)   // padded-CSR capacity (rows padded to mult of 4)
#define HALFN (NN / 2)
#define NEG_SLOPE 0.2f
#define SCB 1024   // elements per scan block
#define RP 8       // regions (one per XCD; blockIdx&7 -> XCD round-robin)
#define RNODES (NN / RP)
#define CHUNK 16384

typedef __attribute__((ext_vector_type(8))) short short8v;   // 8 bf16 (4 VGPRs)
typedef __attribute__((ext_vector_type(4))) float float4v;   // MFMA acc
typedef __attribute__((ext_vector_type(2))) float float2v;

__device__ __forceinline__ float lrelu(float x) { return x > 0.f ? x : NEG_SLOPE * x; }

// ---- bf16 helpers ----
__device__ __forceinline__ uint16_t f2bf(float f) {
  uint32_t u = __float_as_uint(f);
  uint32_t r = u + 0x7fffu + ((u >> 16) & 1u);
  return (uint16_t)(r >> 16);
}
__device__ __forceinline__ float bflo(uint32_t u) { return __uint_as_float(u << 16); }
__device__ __forceinline__ float bfhi(uint32_t u) { return __uint_as_float(u & 0xffff0000u); }
__device__ __forceinline__ float bfs(uint16_t u) { return __uint_as_float((uint32_t)u << 16); }

// ---------------- GEMM f32 in, bf16 out, M=16 (GCN) ----------------
template<int K, int M>
__launch_bounds__(256)
__global__ void gemm4b_kernel(const float* __restrict__ X, const float* __restrict__ W,
                              uint16_t* __restrict__ Y, int n) {
  constexpr int CG = M / 4;
  constexpr int RG = 256 / CG;
  constexpr int RPT = 2;
  constexpr int RT = RG * RPT;
  constexpr int KP = K + 1;
  __shared__ __align__(16) float sW[K * M];
  __shared__ float sX[RT * KP];
  if (blockIdx.x == 0 && threadIdx.x < M)        // zero pad row NN
    Y[(size_t)n * M + threadIdx.x] = 0;
  for (int i = threadIdx.x; i < K * M; i += 256) sW[i] = W[i];
  const int jg = threadIdx.x % CG;
  const int rg = threadIdx.x / CG;
  const int r0 = rg * RPT;
  for (int base = blockIdx.x * RT; base < n; base += gridDim.x * RT) {
    __syncthreads();
    const int nrows = (n - base) < RT ? (n - base) : RT;
    for (int i = threadIdx.x; i < nrows * K; i += 256) {
      int r = i / K, c = i - r * K;
      sX[r * KP + c] = X[(size_t)base * K + i];
    }
    __syncthreads();
    float acc[RPT][4];
    #pragma unroll
    for (int rr = 0; rr < RPT; ++rr) acc[rr][0] = acc[rr][1] = acc[rr][2] = acc[rr][3] = 0.f;
    #pragma unroll 4
    for (int k = 0; k < K; ++k) {
      const float4 w = *(const float4*)&sW[k * M + jg * 4];
      #pragma unroll
      for (int rr = 0; rr < RPT; ++rr) {
        const float xv = sX[(r0 + rr) * KP + k];
        acc[rr][0] = fmaf(xv, w.x, acc[rr][0]);
        acc[rr][1] = fmaf(xv, w.y, acc[rr][1]);
        acc[rr][2] = fmaf(xv, w.z, acc[rr][2]);
        acc[rr][3] = fmaf(xv, w.w, acc[rr][3]);
      }
    }
    #pragma unroll
    for (int rr = 0; rr < RPT; ++rr) {
      if (r0 + rr < nrows) {
        ushort4 o;
        o.x = f2bf(acc[rr][0]); o.y = f2bf(acc[rr][1]);
        o.z = f2bf(acc[rr][2]); o.w = f2bf(acc[rr][3]);
        *(ushort4*)&Y[(size_t)(base + r0 + rr) * M + jg * 4] = o;
      }
    }
  }
}

// ------- pack all three W matrices into B-fragment order (one launch) -------
__launch_bounds__(256)
__global__ void wpack_all_kernel(const float* __restrict__ W0, const float* __restrict__ W1,
                                 const float* __restrict__ W2, uint16_t* __restrict__ wp) {
  int tid = blockIdx.x * 256 + threadIdx.x;
  const float* W; int Kreal, KB, base, t;
  if (tid < 512)       { W = W0; Kreal = 16;  KB = 1; base = 0;     t = tid; }
  else if (tid < 2560) { W = W1; Kreal = 128; KB = 4; base = 4096;  t = tid - 512; }
  else if (tid < 4608) { W = W2; Kreal = 128; KB = 4; base = 20480; t = tid - 2560; }
  else return;
  int lane = t & 63;
  int ctkb = t >> 6;
  int kb = ctkb % KB, ct = ctkb / KB;
  int nc = ct * 16 + (lane & 15);
  int k0 = kb * 32 + (lane >> 4) * 8;
  uint16_t v[8];
  #pragma unroll
  for (int j = 0; j < 8; ++j) {
    int k = k0 + j;
    v[j] = (k < Kreal) ? f2bf(W[(size_t)k * 128 + nc]) : (uint16_t)0;
  }
  ushort4 o0, o1;
  o0.x = v[0]; o0.y = v[1]; o0.z = v[2]; o0.w = v[3];
  o1.x = v[4]; o1.y = v[5]; o1.z = v[6]; o1.w = v[7];
  *(ushort4*)&wp[(size_t)base + (size_t)t * 8] = o0;
  *(ushort4*)&wp[(size_t)base + (size_t)t * 8 + 4] = o1;
}

// ------- MFMA GEMM + fused scores: Y=X@W (bf16), S/T per node-head -------
template<int KB, int XS>   // KB: K/32 blocks; XS: X row stride in bf16 elems
__launch_bounds__(256)
__global__ void gemm_mfma_kernel(const uint16_t* __restrict__ X,
                                 const uint16_t* __restrict__ wp,
                                 const float* __restrict__ aS, const float* __restrict__ aD,
                                 uint16_t* __restrict__ Y,
                                 float* __restrict__ S, float* __restrict__ T, int n) {
  __shared__ float sC[4][16 * 136];
  const int wv = threadIdx.x >> 6;
  const int lane = threadIdx.x & 63;
  const int rowbase = blockIdx.x * 64 + wv * 16;
  int arow = rowbase + (lane & 15);
  if (arow >= n) arow = n - 1;
  const uint16_t* xp = X + (size_t)arow * XS + ((lane >> 4) * 8);
  short8v a[KB];
  #pragma unroll
  for (int kb = 0; kb < KB; ++kb) a[kb] = *(const short8v*)(xp + kb * 32);
  #pragma unroll
  for (int ct = 0; ct < 8; ++ct) {
    float4v acc = {0.f, 0.f, 0.f, 0.f};
    #pragma unroll
    for (int kb = 0; kb < KB; ++kb) {
      short8v b = *(const short8v*)&wp[(size_t)((ct * KB + kb) * 64 + lane) * 8];
      acc = __builtin_amdgcn_mfma_f32_16x16x32_bf16(a[kb], b, acc, 0, 0, 0);
    }
    #pragma unroll
    for (int r = 0; r < 4; ++r)
      sC[wv][((lane >> 4) * 4 + r) * 136 + ct * 16 + (lane & 15)] = acc[r];
  }
  // ---- pack & store h row (bf16) ----
  #pragma unroll
  for (int t = 0; t < 4; ++t) {
    int idx = t * 64 + lane;
    int row = idx >> 4;
    int c8 = idx & 15;
    const float* pr = &sC[wv][row * 136 + c8 * 8];
    float4 lo = *(const float4*)pr;
    float4 hi = *(const float4*)(pr + 4);
    uint4 o;
    o.x = (uint32_t)f2bf(lo.x) | ((uint32_t)f2bf(lo.y) << 16);
    o.y = (uint32_t)f2bf(lo.z) | ((uint32_t)f2bf(lo.w) << 16);
    o.z = (uint32_t)f2bf(hi.x) | ((uint32_t)f2bf(hi.y) << 16);
    o.w = (uint32_t)f2bf(hi.z) | ((uint32_t)f2bf(hi.w) << 16);
    *(uint4*)&Y[(size_t)(rowbase + row) * 128 + c8 * 8] = o;
  }
  // ---- fused scores: lane = (row=lane&15, head-group=lane>>4 -> 2 heads) ----
  {
    int r = lane & 15;
    int hg = lane >> 4;
    int node = rowbase + r;
    if (node < n) {
      #pragma unroll
      for (int hh = 0; hh < 2; ++hh) {
        int h = hg * 2 + hh;
        float sv = 0.f, tv = 0.f;
        #pragma unroll
        for (int c = 0; c < 16; ++c) {
          float v = sC[wv][r * 136 + h * 16 + c];
          sv = fmaf(v, aS[h * 16 + c], sv);
          tv = fmaf(v, aD[h * 16 + c], tv);
        }
        S[(size_t)node * 8 + h] = sv;
        T[(size_t)node * 8 + h] = tv;
      }
    }
  }
}

// ------- GEMM M=2 + fused H=1 scores (g4): Y[n,2], S[n], T[n] -------
template<int K, int ROWS>
__launch_bounds__(256)
__global__ void gemm_s2_kernel(const uint16_t* __restrict__ Xb, const float* __restrict__ W,
                               const float* __restrict__ aS, const float* __restrict__ aD,
                               float* __restrict__ Y, float* __restrict__ S,
                               float* __restrict__ T, int n) {
  constexpr int KP = K + 1;
  __shared__ float sW[K * 2];
  __shared__ float sX[ROWS * KP];
  if (blockIdx.x == 0 && threadIdx.x == 0) {   // pad-row init (sn=NN)
    S[NN] = -1e30f; T[NN] = 0.f;
    Y[(size_t)NN * 2] = 0.f; Y[(size_t)NN * 2 + 1] = 0.f;
  }
  for (int i = threadIdx.x; i < K * 2; i += 256) sW[i] = W[i];
  const float as0 = aS[0], as1 = aS[1], ad0 = aD[0], ad1 = aD[1];
  for (int base = blockIdx.x * ROWS; base < n; base += gridDim.x * ROWS) {
    __syncthreads();
    const int nrows = (n - base) < ROWS ? (n - base) : ROWS;
    for (int i = threadIdx.x; i < nrows * (K / 4); i += 256) {
      int r = i / (K / 4), c = i - r * (K / 4);
      uint2 u = *(const uint2*)&Xb[(size_t)(base + r) * K + c * 4];
      sX[r * KP + c * 4 + 0] = bflo(u.x);
      sX[r * KP + c * 4 + 1] = bfhi(u.x);
      sX[r * KP + c * 4 + 2] = bflo(u.y);
      sX[r * KP + c * 4 + 3] = bfhi(u.y);
    }
    __syncthreads();
    for (int r = threadIdx.x; r < nrows; r += 256) {
      float a0 = 0.f, a1 = 0.f;
      #pragma unroll 4
      for (int k = 0; k < K; ++k) {
        float xv = sX[r * KP + k];
        a0 = fmaf(xv, sW[k * 2], a0);
        a1 = fmaf(xv, sW[k * 2 + 1], a1);
      }
      int node = base + r;
      float2 o; o.x = a0; o.y = a1;
      *(float2*)&Y[(size_t)node * 2] = o;
      S[node] = a0 * as0 + a1 * as1;
      T[node] = a0 * ad0 + a1 * ad1;
    }
  }
}

// ================= CSR build (rows padded to mult of 4) =================
// region-partitioned degree count: block (p,c) counts chunk c's edges with
// dst in region p. All blocks with region p run on XCD p (blockIdx&7 round-
// robin) -> cursor slice (50 KB) stays in that XCD's L2, atomics are local.
__launch_bounds__(256)
__global__ void deg_part_kernel(const int* __restrict__ edst, int* __restrict__ degi) {
  int p = blockIdx.x & (RP - 1);
  int c = blockIdx.x >> 3;
  int lo = p * RNODES, hi = lo + RNODES;
  int e0 = c * CHUNK;
  int e1 = e0 + CHUNK < ET ? e0 + CHUNK : ET;
  for (int e = e0 + threadIdx.x; e < e1; e += 256) {
    int dn = e < NE ? edst[e] : e - NE;
    if (dn >= lo && dn < hi) atomicAdd(&degi[dn], 1);
  }
}

__device__ __forceinline__ int pad4i(int d) { return (d + 3) & ~3; }

__launch_bounds__(256)
__global__ void scan1_kernel(const int* __restrict__ degi, int* __restrict__ rowptr,
                             int* __restrict__ bsums) {
  __shared__ int sd[256];
  int t = threadIdx.x;
  int base = blockIdx.x * SCB + t * 4;
  int v0 = base + 0 < NN ? pad4i(degi[base + 0]) : 0;
  int v1 = base + 1 < NN ? pad4i(degi[base + 1]) : 0;
  int v2 = base + 2 < NN ? pad4i(degi[base + 2]) : 0;
  int v3 = base + 3 < NN ? pad4i(degi[base + 3]) : 0;
  int s = v0 + v1 + v2 + v3;
  sd[t] = s;
  __syncthreads();
  for (int off = 1; off < 256; off <<= 1) {
    int x = (t >= off) ? sd[t - off] : 0;
    __syncthreads();
    sd[t] += x;
    __syncthreads();
  }
  int excl = sd[t] - s;
  if (t == 255) bsums[blockIdx.x] = sd[255];
  if (base + 0 < NN) rowptr[base + 0] = excl;
  excl += v0;
  if (base + 1 < NN) rowptr[base + 1] = excl;
  excl += v1;
  if (base + 2 < NN) rowptr[base + 2] = excl;
  excl += v2;
  if (base + 3 < NN) rowptr[base + 3] = excl;
}

__launch_bounds__(256)
__global__ void scan2_kernel(int* __restrict__ bsums, int nb) {
  __shared__ int sd[256];
  int t = threadIdx.x;
  int v = t < nb ? bsums[t] : 0;
  sd[t] = v;
  __syncthreads();
  for (int off = 1; off < 256; off <<= 1) {
    int x = (t >= off) ? sd[t - off] : 0;
    __syncthreads();
    sd[t] += x;
    __syncthreads();
  }
  if (t < nb) bsums[t] = sd[t] - v;       // exclusive
  if (t == nb - 1) bsums[nb] = sd[t];     // total (padded ET)
}

// scan3 merged: final rowptr + dinv + pad-slot fill + pad-row score init
__launch_bounds__(256)
__global__ void scan3_kernel(int* __restrict__ rowptr, const int* __restrict__ bsums, int nb,
                             const int* __restrict__ deg, float* __restrict__ dinv,
                             float* __restrict__ S8, float* __restrict__ T8,
                             int* __restrict__ csr) {
  int i = blockIdx.x * 256 + threadIdx.x;
  if (i == 0) {
    rowptr[NN] = bsums[nb];
    dinv[NN] = 0.f;
    #pragma unroll
    for (int h = 0; h < 8; ++h) {
      S8[(size_t)NN * 8 + h] = -1e30f;
      T8[(size_t)NN * 8 + h] = 0.f;
    }
  }
  if (i >= NN) return;
  int rp = rowptr[i] + bsums[i / SCB];
  rowptr[i] = rp;
  int dg = deg[i];
  dinv[i] = dg > 0 ? rsqrtf((float)dg) : 0.f;
  int pe = rp + pad4i(dg);
  for (int e = rp + dg; e < pe; ++e) csr[e] = NN;   // dummy src
}

// region-partitioned scatter with XCD-local cursor atomics (row order arbitrary)
__launch_bounds__(256)
__global__ void scatter_part_kernel(const int* __restrict__ esrc, const int* __restrict__ edst,
                                    const int* __restrict__ rowptr, int* __restrict__ cur2,
                                    int* __restrict__ csr_src) {
  int p = blockIdx.x & (RP - 1);
  int c = blockIdx.x >> 3;
  int lo = p * RNODES, hi = lo + RNODES;
  int e0 = c * CHUNK;
  int e1 = e0 + CHUNK < ET ? e0 + CHUNK : ET;
  for (int e = e0 + threadIdx.x; e < e1; e += 256) {
    int dn = e < NE ? edst[e] : e - NE;
    if (dn >= lo && dn < hi) {
      int sn = e < NE ? esrc[e] : e - NE;
      int slot = rowptr[dn] + atomicAdd(&cur2[dn], 1);
      csr_src[slot] = sn;
    }
  }
}

// ====== fused attn+pull v6 (H=8,C=16): online softmax, 2 chains, pad4 tail ====
__launch_bounds__(256)
__global__ void fused_gat_kernel(const int* __restrict__ rowptr, const int* __restrict__ csr,
                                 const float* __restrict__ S, const float* __restrict__ T,
                                 const uint16_t* __restrict__ Hm, const float* __restrict__ bias,
                                 uint16_t* __restrict__ Outb) {
  const int lane = threadIdx.x & 63;
  const int d = (blockIdx.x * 256 + threadIdx.x) >> 6;
  if (d >= NN) return;
  const int rs = rowptr[d];
  const int deg = rowptr[d + 1] - rs;      // multiple of 4
  const int deg8 = deg & ~7;
  const int eg = lane >> 4;
  const int cl = lane & 15;
  const int hp = cl >> 1;
  const float Th = T[(size_t)d * 8 + hp];
  const char* sb = (const char*)S;
  const char* hb = (const char*)Hm;
  float m = -1e38f;
  float s = 0.f;
  float2v A0 = {0.f, 0.f}, A1 = {0.f, 0.f}, A2 = {0.f, 0.f}, A3 = {0.f, 0.f};
  const uint32_t clo = (uint32_t)(cl << 4);
  const uint32_t hpo = (uint32_t)(hp << 2);
  int iA = rs + eg;
  int snA = csr[iA];
  int snB = csr[iA + 4];
  for (int l0 = 0; l0 < deg8; l0 += 8) {
    int snA2 = csr[iA + 8];                                       // prefetch
    int snB2 = csr[iA + 12];
    uint4 uA = *(const uint4*)(hb + (((uint32_t)snA << 8) + clo));
    uint4 uB = *(const uint4*)(hb + (((uint32_t)snB << 8) + clo));
    float svA = *(const float*)(sb + (((uint32_t)snA << 5) + hpo));
    float svB = *(const float*)(sb + (((uint32_t)snB << 5) + hpo));
    iA += 8;
    float eA = lrelu(svA + Th);
    float eB = lrelu(svB + Th);
    float nm = fmaxf(m, fmaxf(eA, eB));    // v_max3
    if (nm > m) {                          // rescale (<=1 per 2 edges)
      float sc = __expf(m - nm);
      float2v scv = {sc, sc};
      s *= sc;
      A0 *= scv; A1 *= scv; A2 *= scv; A3 *= scv;
      m = nm;
    }
    float pA = __expf(eA - m);
    float pB = __expf(eB - m);
    s += pA + pB;
    float2v ppA = {pA, pA}, ppB = {pB, pB};
    A0 = ppA * (float2v){bflo(uA.x), bfhi(uA.x)} + A0;
    A1 = ppA * (float2v){bflo(uA.y), bfhi(uA.y)} + A1;
    A2 = ppA * (float2v){bflo(uA.z), bfhi(uA.z)} + A2;
    A3 = ppA * (float2v){bflo(uA.w), bfhi(uA.w)} + A3;
    A0 = ppB * (float2v){bflo(uB.x), bfhi(uB.x)} + A0;
    A1 = ppB * (float2v){bflo(uB.y), bfhi(uB.y)} + A1;
    A2 = ppB * (float2v){bflo(uB.z), bfhi(uB.z)} + A2;
    A3 = ppB * (float2v){bflo(uB.w), bfhi(uB.w)} + A3;
    snA = snA2; snB = snB2;
  }
  if (deg & 4) {   // 4-edge tail (single chain; snA = csr[rs+deg8+eg])
    uint4 uA = *(const uint4*)(hb + (((uint32_t)snA << 8) + clo));
    float svA = *(const float*)(sb + (((uint32_t)snA << 5) + hpo));
    float eA = lrelu(svA + Th);
    float nm = fmaxf(m, eA);
    if (nm > m) {
      float sc = __expf(m - nm);
      float2v scv = {sc, sc};
      s *= sc;
      A0 *= scv; A1 *= scv; A2 *= scv; A3 *= scv;
      m = nm;
    }
    float pA = __expf(eA - m);
    s += pA;
    float2v ppA = {pA, pA};
    A0 = ppA * (float2v){bflo(uA.x), bfhi(uA.x)} + A0;
    A1 = ppA * (float2v){bflo(uA.y), bfhi(uA.y)} + A1;
    A2 = ppA * (float2v){bflo(uA.z), bfhi(uA.z)} + A2;
    A3 = ppA * (float2v){bflo(uA.w), bfhi(uA.w)} + A3;
  }
  // ---- flash combine across eg lanes (masks 16, 32) ----
  #pragma unroll
  for (int mask = 16; mask <= 32; mask <<= 1) {
    float om = __shfl_xor(m, mask);
    float os = __shfl_xor(s, mask);
    float o0x = __shfl_xor(A0.x, mask), o0y = __shfl_xor(A0.y, mask);
    float o1x = __shfl_xor(A1.x, mask), o1y = __shfl_xor(A1.y, mask);
    float o2x = __shfl_xor(A2.x, mask), o2y = __shfl_xor(A2.y, mask);
    float o3x = __shfl_xor(A3.x, mask), o3y = __shfl_xor(A3.y, mask);
    float nm = fmaxf(m, om);
    float s1 = __expf(m - nm), s2 = __expf(om - nm);
    s = s * s1 + os * s2;
    A0.x = A0.x * s1 + o0x * s2; A0.y = A0.y * s1 + o0y * s2;
    A1.x = A1.x * s1 + o1x * s2; A1.y = A1.y * s1 + o1y * s2;
    A2.x = A2.x * s1 + o2x * s2; A2.y = A2.y * s1 + o2y * s2;
    A3.x = A3.x * s1 + o3x * s2; A3.y = A3.y * s1 + o3y * s2;
    m = nm;
  }
  // ---- spread epilogue: lane (eg,cl) owns channel pair cl*8 + eg*2 ----
  {
    float2v Blo = (eg & 1) ? A1 : A0;
    float2v Bhi = (eg & 1) ? A3 : A2;
    float2v B = (eg & 2) ? Bhi : Blo;
    const float inv = 1.f / (s + 1e-16f);
    float2 b = *(const float2*)&bias[cl * 8 + eg * 2];
    float v0 = fmaf(B.x, inv, b.x);
    float v1 = fmaf(B.y, inv, b.y);
    v0 = v0 > 0.f ? v0 : expm1f(v0);
    v1 = v1 > 0.f ? v1 : expm1f(v1);
    uint32_t o = (uint32_t)f2bf(v0) | ((uint32_t)f2bf(v1) << 16);
    *(uint32_t*)&Outb[(size_t)d * 128 + cl * 8 + eg * 2] = o;
  }
}

// ====== fused attn+pull (H=1, C=2) for g4: 4 nodes/wave, online softmax ======
__launch_bounds__(256)
__global__ void fused_gat1_kernel(const int* __restrict__ rowptr, const int* __restrict__ csr,
                                  const float* __restrict__ S, const float* __restrict__ T,
                                  const float* __restrict__ Hm2, const float* __restrict__ bias,
                                  float* __restrict__ Out) {
  int lane = threadIdx.x & 63;
  int sub = lane >> 4, l16 = lane & 15;
  int d = ((blockIdx.x * 256 + threadIdx.x) >> 6) * 4 + sub;
  if (d >= NN) return;
  int rs = rowptr[d], deg = rowptr[d + 1] - rs;
  float Td = T[d];
  float m = -1e38f, sAcc = 0.f, a0 = 0.f, a1 = 0.f;
  for (int l = l16; l < deg; l += 16) {
    int sn = csr[rs + l];
    float2 hv = *(const float2*)&Hm2[(size_t)sn * 2];
    float sv = S[sn];
    float e = lrelu(sv + Td);
    float nm = fmaxf(m, e);
    if (e > m) {
      float sc = __expf(m - nm);
      sAcc *= sc; a0 *= sc; a1 *= sc; m = nm;
    }
    float p = __expf(e - m);
    sAcc += p;
    a0 = fmaf(p, hv.x, a0);
    a1 = fmaf(p, hv.y, a1);
  }
  #pragma unroll
  for (int mask = 1; mask <= 8; mask <<= 1) {
    float om = __shfl_xor(m, mask);
    float os = __shfl_xor(sAcc, mask);
    float oa0 = __shfl_xor(a0, mask);
    float oa1 = __shfl_xor(a1, mask);
    float nm = fmaxf(m, om);
    float s1 = __expf(m - nm), s2 = __expf(om - nm);
    sAcc = sAcc * s1 + os * s2;
    a0 = a0 * s1 + oa0 * s2;
    a1 = a1 * s1 + oa1 * s2;
    m = nm;
  }
  if (l16 == 0) {
    float inv = 1.f / (sAcc + 1e-16f);
    float v0 = fmaf(a0, inv, bias[0]);
    float v1 = fmaf(a1, inv, bias[1]);
    v0 = v0 > 0.f ? v0 : expm1f(v0);
    v1 = v1 > 0.f ? v1 : expm1f(v1);
    float2 o; o.x = v0; o.y = v1;
    *(float2*)&Out[(size_t)d * 2] = o;
  }
}

// ========== GCN pull (16 thr/node, 4-edge unroll; bf16 table, dinv[NN]=0) =====
// writes bf16 out [N][32] with cols 16..31 zero (g1 MFMA input, K padded to 32)
__launch_bounds__(256)
__global__ void gcn_pull_kernel(const int* __restrict__ rowptr, const int* __restrict__ csr_src,
                                const float* __restrict__ dinv, const uint16_t* __restrict__ Hm,
                                const float* __restrict__ bias, uint16_t* __restrict__ Outb) {
  int d = blockIdx.x * 16 + threadIdx.x / 16;
  if (d >= NN) return;
  int f = threadIdx.x & 15;
  int rs = rowptr[d], re = rowptr[d + 1];
  float acc = 0.f;
  int j = rs;
  for (; j + 4 <= re; j += 4) {
    int s0 = csr_src[j], s1 = csr_src[j + 1], s2 = csr_src[j + 2], s3 = csr_src[j + 3];
    float d0 = dinv[s0], d1 = dinv[s1], d2 = dinv[s2], d3 = dinv[s3];
    float h0 = bfs(Hm[(size_t)s0 * 16 + f]), h1 = bfs(Hm[(size_t)s1 * 16 + f]);
    float h2 = bfs(Hm[(size_t)s2 * 16 + f]), h3 = bfs(Hm[(size_t)s3 * 16 + f]);
    acc = fmaf(d0, h0, acc); acc = fmaf(d1, h1, acc);
    acc = fmaf(d2, h2, acc); acc = fmaf(d3, h3, acc);
  }
  for (; j < re; ++j) {
    int sn = csr_src[j];
    acc = fmaf(dinv[sn], bfs(Hm[(size_t)sn * 16 + f]), acc);
  }
  float v = acc * dinv[d] + bias[f];
  v = v > 0.f ? v : expm1f(v);
  Outb[(size_t)d * 32 + f] = f2bf(v);
  Outb[(size_t)d * 32 + 16 + f] = 0;
}

// ---------------- final concat + log_softmax ----------------
__launch_bounds__(256)
__global__ void final_kernel(const float* __restrict__ A, float* __restrict__ Out) {
  int i = blockIdx.x * 256 + threadIdx.x;
  if (i >= HALFN) return;
  float v0 = A[(size_t)i * 2 + 0];
  float v1 = A[(size_t)i * 2 + 1];
  float v2 = A[(size_t)(i + HALFN) * 2 + 0];
  float v3 = A[(size_t)(i + HALFN) * 2 + 1];
  float m = fmaxf(fmaxf(v0, v1), fmaxf(v2, v3));
  float e0 = __expf(v0 - m), e1 = __expf(v1 - m), e2 = __expf(v2 - m), e3 = __expf(v3 - m);
  float l = logf(e0 + e1 + e2 + e3) + m;
  Out[(size_t)i * 4 + 0] = v0 - l;
  Out[(size_t)i * 4 + 1] = v1 - l;
  Out[(size_t)i * 4 + 2] = v2 - l;
  Out[(size_t)i * 4 + 3] = v3 - l;
}

extern "C" void kernel_launch(void* const* d_in, const int* in_sizes, int n_in,
                              void* d_out, int out_size, void* d_ws, size_t ws_size,
                              hipStream_t stream) {
  const float* x     = (const float*)d_in[0];
  const int*   eidx  = (const int*)d_in[1];
  const int*   esrc  = eidx;
  const int*   edst  = eidx + NE;
  const float* gcn_w = (const float*)d_in[2];
  const float* gcn_b = (const float*)d_in[3];

  char* ws = (char*)d_ws;
  uint16_t* hbf    = (uint16_t*)(ws + 0);            // [NPAD][128] bf16 (post-GEMM h)
  uint16_t* bufAb  = (uint16_t*)(ws + 25700000);     // [NPAD][128] bf16 (GAT layer out)
  uint16_t* gcnHbf = (uint16_t*)(ws + 51400000);     // [NN][32] bf16 (g1 X, K-padded)
  float*    bufB   = (float*)   (ws + 57900000);     // [NN+1][16] (GCN h bf16 / g4 h f32)
  float*    bufC   = (float*)   (ws + 64400000);     // [NN][2] f32 (g4 out)
  float*    Sb     = (float*)   (ws + 65300000);     // NN*8+8
  float*    Tb     = (float*)   (ws + 68600000);     // NN*8+8
  uint16_t* wpck   = (uint16_t*)(ws + 71900000);     // 72KB (all-layer B-fragments)
  int*      rowptr = (int*)     (ws + 151900000);    // NN+1 (padded CSR)
  int*      cursor = (int*)     (ws + 152300008);    // NN (real degrees)
  int*      cur2   = (int*)     (ws + 152700008);    // NN (scatter cursors)
  int*      csr    = (int*)     (ws + 153100008);    // ETP_MAX
  float*    dinv   = (float*)   (ws + 163500016);    // NN+1
  int*      bsums  = (int*)     (ws + 163900024);    // NB+1
  uint16_t* w0p    = wpck;                           // elem 0
  uint16_t* w1p    = wpck + 4096;
  uint16_t* w2p    = wpck + 20480;

  constexpr int NB_SCAN = (NN + SCB - 1) / SCB;  // 98
  const int nch = (ET + CHUNK - 1) / CHUNK;

  // ---------------- CSR build (XCD-local atomics) ----------------
  hipMemsetAsync(cursor, 0, (size_t)NN * 8, stream);   // cursor + cur2 (adjacent)
  deg_part_kernel<<<nch * RP, 256, 0, stream>>>(edst, cursor);
  scan1_kernel<<<NB_SCAN, 256, 0, stream>>>(cursor, rowptr, bsums);
  scan2_kernel<<<1, 256, 0, stream>>>(bsums, NB_SCAN);
  scan3_kernel<<<(NN + 256) / 256, 256, 0, stream>>>(rowptr, bsums, NB_SCAN,
                                                     cursor, dinv, Sb, Tb, csr);
  scatter_part_kernel<<<nch * RP, 256, 0, stream>>>(esrc, edst, rowptr, cur2, csr);
  // all-layer W pack (independent of CSR; single launch)
  wpack_all_kernel<<<18, 256, 0, stream>>>((const float*)d_in[4], (const float*)d_in[8],
                                           (const float*)d_in[12], wpck);

  // ---------------- GCN: x[n,128] -> gcnHbf[n,32] bf16 ----------------
  {
    int tiles = (NN + 127) / 128;
    if (tiles > 4096) tiles = 4096;
    gemm4b_kernel<128, 16><<<tiles, 256, 0, stream>>>(x, gcn_w, (uint16_t*)bufB, NN);
  }
  gcn_pull_kernel<<<(NN + 15) / 16, 256, 0, stream>>>(rowptr, csr, dinv,
                                                      (const uint16_t*)bufB, gcn_b, gcnHbf);

  // ---------------- GAT g1 (K=16->32, MFMA + fused scores) ----------------
  gemm_mfma_kernel<1, 32><<<NPAD / 64, 256, 0, stream>>>(
      gcnHbf, w0p, (const float*)d_in[5], (const float*)d_in[6], hbf, Sb, Tb, NN);
  fused_gat_kernel<<<(NN * 64 + 255) / 256, 256, 0, stream>>>(
      rowptr, csr, Sb, Tb, hbf, (const float*)d_in[7], bufAb);

  // ---------------- GAT g2 (K=128, MFMA + fused scores) ----------------
  gemm_mfma_kernel<4, 128><<<NPAD / 64, 256, 0, stream>>>(
      bufAb, w1p, (const float*)d_in[9], (const float*)d_in[10], hbf, Sb, Tb, NN);
  fused_gat_kernel<<<(NN * 64 + 255) / 256, 256, 0, stream>>>(
      rowptr, csr, Sb, Tb, hbf, (const float*)d_in[11], bufAb);

  // ---------------- GAT g3 (K=128, MFMA + fused scores) ----------------
  gemm_mfma_kernel<4, 128><<<NPAD / 64, 256, 0, stream>>>(
      bufAb, w2p, (const float*)d_in[13], (const float*)d_in[14], hbf, Sb, Tb, NN);
  fused_gat_kernel<<<(NN * 64 + 255) / 256, 256, 0, stream>>>(
      rowptr, csr, Sb, Tb, hbf, (const float*)d_in[15], bufAb);

  // ---------------- GAT g4 (H=1, C=2, fused gemm+score then attn+pull) --------
  {
    int tiles = (NN + 127) / 128;
    if (tiles > 2048) tiles = 2048;
    gemm_s2_kernel<128, 128><<<tiles, 256, 0, stream>>>(
        bufAb, (const float*)d_in[16], (const float*)d_in[17], (const float*)d_in[18],
        bufB, Sb, Tb, NN);
    fused_gat1_kernel<<<(NN * 16 + 255) / 256, 256, 0, stream>>>(
        rowptr, csr, Sb, Tb, bufB, (const float*)d_in[19], bufC);
  }

  // ---------------- concat + log_softmax -> d_out [HALFN,4] ----------------
  final_kernel<<<(HALFN + 255) / 256, 256, 0, stream>>>(bufC, (float*)d_out);
}

// Round 13
// 493.704 us; speedup vs baseline: 1.0787x; 1.0787x over previous
//
#include <hip/hip_runtime.h>
#include <cstddef>
#include <cstdint>

#define NN 100000
#define NPAD 100032          // NN rounded to 64 (gemm row tiles)
#define NE 1600000
#define ET (NE + NN)
#define ETP_MAX (ET + 8 * NN)   // padded-CSR capacity (rows padded to mult of 4)
#define HALFN (NN / 2)
#define NEG_SLOPE 0.2f
#define SCB 1024   // elements per scan block
#define RP 8       // scatter regions (one per XCD)
#define RNODES (NN / RP)
#define CHUNK 8192

typedef __attribute__((ext_vector_type(8))) short short8v;   // 8 bf16 (4 VGPRs)
typedef __attribute__((ext_vector_type(4))) float float4v;   // MFMA acc
typedef __attribute__((ext_vector_type(2))) float float2v;

__device__ __forceinline__ float lrelu(float x) { return x > 0.f ? x : NEG_SLOPE * x; }

// ---- bf16 helpers ----
__device__ __forceinline__ uint16_t f2bf(float f) {
  uint32_t u = __float_as_uint(f);
  uint32_t r = u + 0x7fffu + ((u >> 16) & 1u);
  return (uint16_t)(r >> 16);
}
__device__ __forceinline__ float bflo(uint32_t u) { return __uint_as_float(u << 16); }
__device__ __forceinline__ float bfhi(uint32_t u) { return __uint_as_float(u & 0xffff0000u); }
__device__ __forceinline__ float bfs(uint16_t u) { return __uint_as_float((uint32_t)u << 16); }

// ---------------- GEMM f32 in, bf16 out, M=16 (GCN) ----------------
template<int K, int M>
__launch_bounds__(256)
__global__ void gemm4b_kernel(const float* __restrict__ X, const float* __restrict__ W,
                              uint16_t* __restrict__ Y, int n) {
  constexpr int CG = M / 4;
  constexpr int RG = 256 / CG;
  constexpr int RPT = 2;
  constexpr int RT = RG * RPT;
  constexpr int KP = K + 1;
  __shared__ __align__(16) float sW[K * M];
  __shared__ float sX[RT * KP];
  if (blockIdx.x == 0 && threadIdx.x < M)        // zero pad row NN
    Y[(size_t)n * M + threadIdx.x] = 0;
  for (int i = threadIdx.x; i < K * M; i += 256) sW[i] = W[i];
  const int jg = threadIdx.x % CG;
  const int rg = threadIdx.x / CG;
  const int r0 = rg * RPT;
  for (int base = blockIdx.x * RT; base < n; base += gridDim.x * RT) {
    __syncthreads();
    const int nrows = (n - base) < RT ? (n - base) : RT;
    for (int i = threadIdx.x; i < nrows * K; i += 256) {
      int r = i / K, c = i - r * K;
      sX[r * KP + c] = X[(size_t)base * K + i];
    }
    __syncthreads();
    float acc[RPT][4];
    #pragma unroll
    for (int rr = 0; rr < RPT; ++rr) acc[rr][0] = acc[rr][1] = acc[rr][2] = acc[rr][3] = 0.f;
    #pragma unroll 4
    for (int k = 0; k < K; ++k) {
      const float4 w = *(const float4*)&sW[k * M + jg * 4];
      #pragma unroll
      for (int rr = 0; rr < RPT; ++rr) {
        const float xv = sX[(r0 + rr) * KP + k];
        acc[rr][0] = fmaf(xv, w.x, acc[rr][0]);
        acc[rr][1] = fmaf(xv, w.y, acc[rr][1]);
        acc[rr][2] = fmaf(xv, w.z, acc[rr][2]);
        acc[rr][3] = fmaf(xv, w.w, acc[rr][3]);
      }
    }
    #pragma unroll
    for (int rr = 0; rr < RPT; ++rr) {
      if (r0 + rr < nrows) {
        ushort4 o;
        o.x = f2bf(acc[rr][0]); o.y = f2bf(acc[rr][1]);
        o.z = f2bf(acc[rr][2]); o.w = f2bf(acc[rr][3]);
        *(ushort4*)&Y[(size_t)(base + r0 + rr) * M + jg * 4] = o;
      }
    }
  }
}

// ------- pack all three W matrices into B-fragment order (one launch) -------
__launch_bounds__(256)
__global__ void wpack_all_kernel(const float* __restrict__ W0, const float* __restrict__ W1,
                                 const float* __restrict__ W2, uint16_t* __restrict__ wp) {
  int tid = blockIdx.x * 256 + threadIdx.x;
  const float* W; int Kreal, KB, base, t;
  if (tid < 512)       { W = W0; Kreal = 16;  KB = 1; base = 0;     t = tid; }
  else if (tid < 2560) { W = W1; Kreal = 128; KB = 4; base = 4096;  t = tid - 512; }
  else if (tid < 4608) { W = W2; Kreal = 128; KB = 4; base = 20480; t = tid - 2560; }
  else return;
  int lane = t & 63;
  int ctkb = t >> 6;
  int kb = ctkb % KB, ct = ctkb / KB;
  int nc = ct * 16 + (lane & 15);
  int k0 = kb * 32 + (lane >> 4) * 8;
  uint16_t v[8];
  #pragma unroll
  for (int j = 0; j < 8; ++j) {
    int k = k0 + j;
    v[j] = (k < Kreal) ? f2bf(W[(size_t)k * 128 + nc]) : (uint16_t)0;
  }
  ushort4 o0, o1;
  o0.x = v[0]; o0.y = v[1]; o0.z = v[2]; o0.w = v[3];
  o1.x = v[4]; o1.y = v[5]; o1.z = v[6]; o1.w = v[7];
  *(ushort4*)&wp[(size_t)base + (size_t)t * 8] = o0;
  *(ushort4*)&wp[(size_t)base + (size_t)t * 8 + 4] = o1;
}

// ------- MFMA GEMM + fused scores: Y=X@W (bf16), S/T per node-head -------
template<int KB, int XS>   // KB: K/32 blocks; XS: X row stride in bf16 elems
__launch_bounds__(256)
__global__ void gemm_mfma_kernel(const uint16_t* __restrict__ X,
                                 const uint16_t* __restrict__ wp,
                                 const float* __restrict__ aS, const float* __restrict__ aD,
                                 uint16_t* __restrict__ Y,
                                 float* __restrict__ S, float* __restrict__ T, int n) {
  __shared__ float sC[4][16 * 136];
  const int wv = threadIdx.x >> 6;
  const int lane = threadIdx.x & 63;
  const int rowbase = blockIdx.x * 64 + wv * 16;
  int arow = rowbase + (lane & 15);
  if (arow >= n) arow = n - 1;
  const uint16_t* xp = X + (size_t)arow * XS + ((lane >> 4) * 8);
  short8v a[KB];
  #pragma unroll
  for (int kb = 0; kb < KB; ++kb) a[kb] = *(const short8v*)(xp + kb * 32);
  #pragma unroll
  for (int ct = 0; ct < 8; ++ct) {
    float4v acc = {0.f, 0.f, 0.f, 0.f};
    #pragma unroll
    for (int kb = 0; kb < KB; ++kb) {
      short8v b = *(const short8v*)&wp[(size_t)((ct * KB + kb) * 64 + lane) * 8];
      acc = __builtin_amdgcn_mfma_f32_16x16x32_bf16(a[kb], b, acc, 0, 0, 0);
    }
    #pragma unroll
    for (int r = 0; r < 4; ++r)
      sC[wv][((lane >> 4) * 4 + r) * 136 + ct * 16 + (lane & 15)] = acc[r];
  }
  // ---- pack & store h row (bf16) ----
  #pragma unroll
  for (int t = 0; t < 4; ++t) {
    int idx = t * 64 + lane;
    int row = idx >> 4;
    int c8 = idx & 15;
    const float* pr = &sC[wv][row * 136 + c8 * 8];
    float4 lo = *(const float4*)pr;
    float4 hi = *(const float4*)(pr + 4);
    uint4 o;
    o.x = (uint32_t)f2bf(lo.x) | ((uint32_t)f2bf(lo.y) << 16);
    o.y = (uint32_t)f2bf(lo.z) | ((uint32_t)f2bf(lo.w) << 16);
    o.z = (uint32_t)f2bf(hi.x) | ((uint32_t)f2bf(hi.y) << 16);
    o.w = (uint32_t)f2bf(hi.z) | ((uint32_t)f2bf(hi.w) << 16);
    *(uint4*)&Y[(size_t)(rowbase + row) * 128 + c8 * 8] = o;
  }
  // ---- fused scores: lane = (row=lane&15, head-group=lane>>4 -> 2 heads) ----
  {
    int r = lane & 15;
    int hg = lane >> 4;
    int node = rowbase + r;
    if (node < n) {
      #pragma unroll
      for (int hh = 0; hh < 2; ++hh) {
        int h = hg * 2 + hh;
        float sv = 0.f, tv = 0.f;
        #pragma unroll
        for (int c = 0; c < 16; ++c) {
          float v = sC[wv][r * 136 + h * 16 + c];
          sv = fmaf(v, aS[h * 16 + c], sv);
          tv = fmaf(v, aD[h * 16 + c], tv);
        }
        S[(size_t)node * 8 + h] = sv;
        T[(size_t)node * 8 + h] = tv;
      }
    }
  }
}

// ------- GEMM M=2 + fused H=1 scores (g4): Y[n,2], S[n], T[n] -------
template<int K, int ROWS>
__launch_bounds__(256)
__global__ void gemm_s2_kernel(const uint16_t* __restrict__ Xb, const float* __restrict__ W,
                               const float* __restrict__ aS, const float* __restrict__ aD,
                               float* __restrict__ Y, float* __restrict__ S,
                               float* __restrict__ T, int n) {
  constexpr int KP = K + 1;
  __shared__ float sW[K * 2];
  __shared__ float sX[ROWS * KP];
  if (blockIdx.x == 0 && threadIdx.x == 0) {   // pad-row init (sn=NN)
    S[NN] = -1e30f; T[NN] = 0.f;
    Y[(size_t)NN * 2] = 0.f; Y[(size_t)NN * 2 + 1] = 0.f;
  }
  for (int i = threadIdx.x; i < K * 2; i += 256) sW[i] = W[i];
  const float as0 = aS[0], as1 = aS[1], ad0 = aD[0], ad1 = aD[1];
  for (int base = blockIdx.x * ROWS; base < n; base += gridDim.x * ROWS) {
    __syncthreads();
    const int nrows = (n - base) < ROWS ? (n - base) : ROWS;
    for (int i = threadIdx.x; i < nrows * (K / 4); i += 256) {
      int r = i / (K / 4), c = i - r * (K / 4);
      uint2 u = *(const uint2*)&Xb[(size_t)(base + r) * K + c * 4];
      sX[r * KP + c * 4 + 0] = bflo(u.x);
      sX[r * KP + c * 4 + 1] = bfhi(u.x);
      sX[r * KP + c * 4 + 2] = bflo(u.y);
      sX[r * KP + c * 4 + 3] = bfhi(u.y);
    }
    __syncthreads();
    for (int r = threadIdx.x; r < nrows; r += 256) {
      float a0 = 0.f, a1 = 0.f;
      #pragma unroll 4
      for (int k = 0; k < K; ++k) {
        float xv = sX[r * KP + k];
        a0 = fmaf(xv, sW[k * 2], a0);
        a1 = fmaf(xv, sW[k * 2 + 1], a1);
      }
      int node = base + r;
      float2 o; o.x = a0; o.y = a1;
      *(float2*)&Y[(size_t)node * 2] = o;
      S[node] = a0 * as0 + a1 * as1;
      T[node] = a0 * ad0 + a1 * ad1;
    }
  }
}

// ================= CSR build (rows padded to multiples of 4) =================
// single atomic pass: per-edge arrival rank; degrees left in cursor
__launch_bounds__(256)
__global__ void rank_kernel(const int* __restrict__ edst, int* __restrict__ cursor,
                            int* __restrict__ rank) {
  int e = blockIdx.x * 256 + threadIdx.x;
  if (e >= ET) return;
  int dn = e < NE ? edst[e] : e - NE;
  rank[e] = atomicAdd(&cursor[dn], 1);
}

__device__ __forceinline__ int pad4i(int d) { return (d + 3) & ~3; }

__launch_bounds__(256)
__global__ void scan1_kernel(const int* __restrict__ degi, int* __restrict__ rowptr,
                             int* __restrict__ bsums) {
  __shared__ int sd[256];
  int t = threadIdx.x;
  int base = blockIdx.x * SCB + t * 4;
  int v0 = base + 0 < NN ? pad4i(degi[base + 0]) : 0;
  int v1 = base + 1 < NN ? pad4i(degi[base + 1]) : 0;
  int v2 = base + 2 < NN ? pad4i(degi[base + 2]) : 0;
  int v3 = base + 3 < NN ? pad4i(degi[base + 3]) : 0;
  int s = v0 + v1 + v2 + v3;
  sd[t] = s;
  __syncthreads();
  for (int off = 1; off < 256; off <<= 1) {
    int x = (t >= off) ? sd[t - off] : 0;
    __syncthreads();
    sd[t] += x;
    __syncthreads();
  }
  int excl = sd[t] - s;
  if (t == 255) bsums[blockIdx.x] = sd[255];
  if (base + 0 < NN) rowptr[base + 0] = excl;
  excl += v0;
  if (base + 1 < NN) rowptr[base + 1] = excl;
  excl += v1;
  if (base + 2 < NN) rowptr[base + 2] = excl;
  excl += v2;
  if (base + 3 < NN) rowptr[base + 3] = excl;
}

__launch_bounds__(256)
__global__ void scan2_kernel(int* __restrict__ bsums, int nb) {
  __shared__ int sd[256];
  int t = threadIdx.x;
  int v = t < nb ? bsums[t] : 0;
  sd[t] = v;
  __syncthreads();
  for (int off = 1; off < 256; off <<= 1) {
    int x = (t >= off) ? sd[t - off] : 0;
    __syncthreads();
    sd[t] += x;
    __syncthreads();
  }
  if (t < nb) bsums[t] = sd[t] - v;       // exclusive
  if (t == nb - 1) bsums[nb] = sd[t];     // total (padded ET)
}

// scan3 merged: final rowptr + dinv + pad-slot fill + pad-row score init
__launch_bounds__(256)
__global__ void scan3_kernel(int* __restrict__ rowptr, const int* __restrict__ bsums, int nb,
                             const int* __restrict__ deg, float* __restrict__ dinv,
                             float* __restrict__ S8, float* __restrict__ T8,
                             int* __restrict__ csr) {
  int i = blockIdx.x * 256 + threadIdx.x;
  if (i == 0) {
    rowptr[NN] = bsums[nb];
    dinv[NN] = 0.f;
    #pragma unroll
    for (int h = 0; h < 8; ++h) {
      S8[(size_t)NN * 8 + h] = -1e30f;
      T8[(size_t)NN * 8 + h] = 0.f;
    }
  }
  if (i >= NN) return;
  int rp = rowptr[i] + bsums[i / SCB];
  rowptr[i] = rp;
  int dg = deg[i];
  dinv[i] = dg > 0 ? rsqrtf((float)dg) : 0.f;
  int pe = rp + pad4i(dg);
  for (int e = rp + dg; e < pe; ++e) csr[e] = NN;   // dummy src
}

// atomic-free partitioned scatter (region-per-XCD write locality)
__launch_bounds__(256)
__global__ void scatter_part_kernel(const int* __restrict__ esrc, const int* __restrict__ edst,
                                    const int* __restrict__ rowptr, const int* __restrict__ rank,
                                    int* __restrict__ csr_src) {
  int p = blockIdx.x & (RP - 1);
  int c = blockIdx.x >> 3;
  int lo = p * RNODES, hi = lo + RNODES;
  int e0 = c * CHUNK;
  int e1 = e0 + CHUNK < ET ? e0 + CHUNK : ET;
  for (int e = e0 + threadIdx.x; e < e1; e += 256) {
    int dn = e < NE ? edst[e] : e - NE;
    if (dn >= lo && dn < hi) {
      int sn = e < NE ? esrc[e] : e - NE;
      csr_src[rowptr[dn] + rank[e]] = sn;
    }
  }
}

// ====== fused attn+pull v6 (H=8,C=16): online softmax, 2 chains, pad4 tail ====
__launch_bounds__(256)
__global__ void fused_gat_kernel(const int* __restrict__ rowptr, const int* __restrict__ csr,
                                 const float* __restrict__ S, const float* __restrict__ T,
                                 const uint16_t* __restrict__ Hm, const float* __restrict__ bias,
                                 uint16_t* __restrict__ Outb) {
  const int lane = threadIdx.x & 63;
  const int d = (blockIdx.x * 256 + threadIdx.x) >> 6;
  if (d >= NN) return;
  const int rs = rowptr[d];
  const int deg = rowptr[d + 1] - rs;      // multiple of 4
  const int deg8 = deg & ~7;
  const int eg = lane >> 4;
  const int cl = lane & 15;
  const int hp = cl >> 1;
  const float Th = T[(size_t)d * 8 + hp];
  const char* sb = (const char*)S;
  const char* hb = (const char*)Hm;
  float m = -1e38f;
  float s = 0.f;
  float2v A0 = {0.f, 0.f}, A1 = {0.f, 0.f}, A2 = {0.f, 0.f}, A3 = {0.f, 0.f};
  const uint32_t clo = (uint32_t)(cl << 4);
  const uint32_t hpo = (uint32_t)(hp << 2);
  int iA = rs + eg;
  int snA = csr[iA];
  int snB = csr[iA + 4];
  for (int l0 = 0; l0 < deg8; l0 += 8) {
    int snA2 = csr[iA + 8];                                       // prefetch
    int snB2 = csr[iA + 12];
    uint4 uA = *(const uint4*)(hb + (((uint32_t)snA << 8) + clo));
    uint4 uB = *(const uint4*)(hb + (((uint32_t)snB << 8) + clo));
    float svA = *(const float*)(sb + (((uint32_t)snA << 5) + hpo));
    float svB = *(const float*)(sb + (((uint32_t)snB << 5) + hpo));
    iA += 8;
    float eA = lrelu(svA + Th);
    float eB = lrelu(svB + Th);
    float nm = fmaxf(m, fmaxf(eA, eB));    // v_max3
    if (nm > m) {                          // rescale (<=1 per 2 edges)
      float sc = __expf(m - nm);
      float2v scv = {sc, sc};
      s *= sc;
      A0 *= scv; A1 *= scv; A2 *= scv; A3 *= scv;
      m = nm;
    }
    float pA = __expf(eA - m);
    float pB = __expf(eB - m);
    s += pA + pB;
    float2v ppA = {pA, pA}, ppB = {pB, pB};
    A0 = ppA * (float2v){bflo(uA.x), bfhi(uA.x)} + A0;
    A1 = ppA * (float2v){bflo(uA.y), bfhi(uA.y)} + A1;
    A2 = ppA * (float2v){bflo(uA.z), bfhi(uA.z)} + A2;
    A3 = ppA * (float2v){bflo(uA.w), bfhi(uA.w)} + A3;
    A0 = ppB * (float2v){bflo(uB.x), bfhi(uB.x)} + A0;
    A1 = ppB * (float2v){bflo(uB.y), bfhi(uB.y)} + A1;
    A2 = ppB * (float2v){bflo(uB.z), bfhi(uB.z)} + A2;
    A3 = ppB * (float2v){bflo(uB.w), bfhi(uB.w)} + A3;
    snA = snA2; snB = snB2;
  }
  if (deg & 4) {   // 4-edge tail (single chain; snA = csr[rs+deg8+eg])
    uint4 uA = *(const uint4*)(hb + (((uint32_t)snA << 8) + clo));
    float svA = *(const float*)(sb + (((uint32_t)snA << 5) + hpo));
    float eA = lrelu(svA + Th);
    float nm = fmaxf(m, eA);
    if (nm > m) {
      float sc = __expf(m - nm);
      float2v scv = {sc, sc};
      s *= sc;
      A0 *= scv; A1 *= scv; A2 *= scv; A3 *= scv;
      m = nm;
    }
    float pA = __expf(eA - m);
    s += pA;
    float2v ppA = {pA, pA};
    A0 = ppA * (float2v){bflo(uA.x), bfhi(uA.x)} + A0;
    A1 = ppA * (float2v){bflo(uA.y), bfhi(uA.y)} + A1;
    A2 = ppA * (float2v){bflo(uA.z), bfhi(uA.z)} + A2;
    A3 = ppA * (float2v){bflo(uA.w), bfhi(uA.w)} + A3;
  }
  // ---- flash combine across eg lanes (masks 16, 32) ----
  #pragma unroll
  for (int mask = 16; mask <= 32; mask <<= 1) {
    float om = __shfl_xor(m, mask);
    float os = __shfl_xor(s, mask);
    float o0x = __shfl_xor(A0.x, mask), o0y = __shfl_xor(A0.y, mask);
    float o1x = __shfl_xor(A1.x, mask), o1y = __shfl_xor(A1.y, mask);
    float o2x = __shfl_xor(A2.x, mask), o2y = __shfl_xor(A2.y, mask);
    float o3x = __shfl_xor(A3.x, mask), o3y = __shfl_xor(A3.y, mask);
    float nm = fmaxf(m, om);
    float s1 = __expf(m - nm), s2 = __expf(om - nm);
    s = s * s1 + os * s2;
    A0.x = A0.x * s1 + o0x * s2; A0.y = A0.y * s1 + o0y * s2;
    A1.x = A1.x * s1 + o1x * s2; A1.y = A1.y * s1 + o1y * s2;
    A2.x = A2.x * s1 + o2x * s2; A2.y = A2.y * s1 + o2y * s2;
    A3.x = A3.x * s1 + o3x * s2; A3.y = A3.y * s1 + o3y * s2;
    m = nm;
  }
  // ---- spread epilogue: lane (eg,cl) owns channel pair cl*8 + eg*2 ----
  {
    float2v Blo = (eg & 1) ? A1 : A0;
    float2v Bhi = (eg & 1) ? A3 : A2;
    float2v B = (eg & 2) ? Bhi : Blo;
    const float inv = 1.f / (s + 1e-16f);
    float2 b = *(const float2*)&bias[cl * 8 + eg * 2];
    float v0 = fmaf(B.x, inv, b.x);
    float v1 = fmaf(B.y, inv, b.y);
    v0 = v0 > 0.f ? v0 : expm1f(v0);
    v1 = v1 > 0.f ? v1 : expm1f(v1);
    uint32_t o = (uint32_t)f2bf(v0) | ((uint32_t)f2bf(v1) << 16);
    *(uint32_t*)&Outb[(size_t)d * 128 + cl * 8 + eg * 2] = o;
  }
}

// ====== fused attn+pull (H=1, C=2) for g4: 4 nodes/wave, online softmax ======
__launch_bounds__(256)
__global__ void fused_gat1_kernel(const int* __restrict__ rowptr, const int* __restrict__ csr,
                                  const float* __restrict__ S, const float* __restrict__ T,
                                  const float* __restrict__ Hm2, const float* __restrict__ bias,
                                  float* __restrict__ Out) {
  int lane = threadIdx.x & 63;
  int sub = lane >> 4, l16 = lane & 15;
  int d = ((blockIdx.x * 256 + threadIdx.x) >> 6) * 4 + sub;
  if (d >= NN) return;
  int rs = rowptr[d], deg = rowptr[d + 1] - rs;
  float Td = T[d];
  float m = -1e38f, sAcc = 0.f, a0 = 0.f, a1 = 0.f;
  for (int l = l16; l < deg; l += 16) {
    int sn = csr[rs + l];
    float2 hv = *(const float2*)&Hm2[(size_t)sn * 2];
    float sv = S[sn];
    float e = lrelu(sv + Td);
    float nm = fmaxf(m, e);
    if (e > m) {
      float sc = __expf(m - nm);
      sAcc *= sc; a0 *= sc; a1 *= sc; m = nm;
    }
    float p = __expf(e - m);
    sAcc += p;
    a0 = fmaf(p, hv.x, a0);
    a1 = fmaf(p, hv.y, a1);
  }
  #pragma unroll
  for (int mask = 1; mask <= 8; mask <<= 1) {
    float om = __shfl_xor(m, mask);
    float os = __shfl_xor(sAcc, mask);
    float oa0 = __shfl_xor(a0, mask);
    float oa1 = __shfl_xor(a1, mask);
    float nm = fmaxf(m, om);
    float s1 = __expf(m - nm), s2 = __expf(om - nm);
    sAcc = sAcc * s1 + os * s2;
    a0 = a0 * s1 + oa0 * s2;
    a1 = a1 * s1 + oa1 * s2;
    m = nm;
  }
  if (l16 == 0) {
    float inv = 1.f / (sAcc + 1e-16f);
    float v0 = fmaf(a0, inv, bias[0]);
    float v1 = fmaf(a1, inv, bias[1]);
    v0 = v0 > 0.f ? v0 : expm1f(v0);
    v1 = v1 > 0.f ? v1 : expm1f(v1);
    float2 o; o.x = v0; o.y = v1;
    *(float2*)&Out[(size_t)d * 2] = o;
  }
}

// ========== GCN pull (16 thr/node, 4-edge unroll; bf16 table, dinv[NN]=0) =====
// writes bf16 out [N][32] with cols 16..31 zero (g1 MFMA input, K padded to 32)
__launch_bounds__(256)
__global__ void gcn_pull_kernel(const int* __restrict__ rowptr, const int* __restrict__ csr_src,
                                const float* __restrict__ dinv, const uint16_t* __restrict__ Hm,
                                const float* __restrict__ bias, uint16_t* __restrict__ Outb) {
  int d = blockIdx.x * 16 + threadIdx.x / 16;
  if (d >= NN) return;
  int f = threadIdx.x & 15;
  int rs = rowptr[d], re = rowptr[d + 1];
  float acc = 0.f;
  int j = rs;
  for (; j + 4 <= re; j += 4) {
    int s0 = csr_src[j], s1 = csr_src[j + 1], s2 = csr_src[j + 2], s3 = csr_src[j + 3];
    float d0 = dinv[s0], d1 = dinv[s1], d2 = dinv[s2], d3 = dinv[s3];
    float h0 = bfs(Hm[(size_t)s0 * 16 + f]), h1 = bfs(Hm[(size_t)s1 * 16 + f]);
    float h2 = bfs(Hm[(size_t)s2 * 16 + f]), h3 = bfs(Hm[(size_t)s3 * 16 + f]);
    acc = fmaf(d0, h0, acc); acc = fmaf(d1, h1, acc);
    acc = fmaf(d2, h2, acc); acc = fmaf(d3, h3, acc);
  }
  for (; j < re; ++j) {
    int sn = csr_src[j];
    acc = fmaf(dinv[sn], bfs(Hm[(size_t)sn * 16 + f]), acc);
  }
  float v = acc * dinv[d] + bias[f];
  v = v > 0.f ? v : expm1f(v);
  Outb[(size_t)d * 32 + f] = f2bf(v);
  Outb[(size_t)d * 32 + 16 + f] = 0;
}

// ---------------- final concat + log_softmax ----------------
__launch_bounds__(256)
__global__ void final_kernel(const float* __restrict__ A, float* __restrict__ Out) {
  int i = blockIdx.x * 256 + threadIdx.x;
  if (i >= HALFN) return;
  float v0 = A[(size_t)i * 2 + 0];
  float v1 = A[(size_t)i * 2 + 1];
  float v2 = A[(size_t)(i + HALFN) * 2 + 0];
  float v3 = A[(size_t)(i + HALFN) * 2 + 1];
  float m = fmaxf(fmaxf(v0, v1), fmaxf(v2, v3));
  float e0 = __expf(v0 - m), e1 = __expf(v1 - m), e2 = __expf(v2 - m), e3 = __expf(v3 - m);
  float l = logf(e0 + e1 + e2 + e3) + m;
  Out[(size_t)i * 4 + 0] = v0 - l;
  Out[(size_t)i * 4 + 1] = v1 - l;
  Out[(size_t)i * 4 + 2] = v2 - l;
  Out[(size_t)i * 4 + 3] = v3 - l;
}

extern "C" void kernel_launch(void* const* d_in, const int* in_sizes, int n_in,
                              void* d_out, int out_size, void* d_ws, size_t ws_size,
                              hipStream_t stream) {
  const float* x     = (const float*)d_in[0];
  const int*   eidx  = (const int*)d_in[1];
  const int*   esrc  = eidx;
  const int*   edst  = eidx + NE;
  const float* gcn_w = (const float*)d_in[2];
  const float* gcn_b = (const float*)d_in[3];

  char* ws = (char*)d_ws;
  uint16_t* hbf    = (uint16_t*)(ws + 0);            // [NPAD][128] bf16 (post-GEMM h)
  uint16_t* bufAb  = (uint16_t*)(ws + 25700000);     // [NPAD][128] bf16 (GAT layer out)
  uint16_t* gcnHbf = (uint16_t*)(ws + 51400000);     // [NN][32] bf16 (g1 X, K-padded)
  float*    bufB   = (float*)   (ws + 57900000);     // [NN+1][16] (GCN h bf16 / g4 h f32)
  float*    bufC   = (float*)   (ws + 64400000);     // [NN][2] f32 (g4 out)
  float*    Sb     = (float*)   (ws + 65300000);     // NN*8+8
  float*    Tb     = (float*)   (ws + 68600000);     // NN*8+8
  uint16_t* wpck   = (uint16_t*)(ws + 71900000);     // 72KB (all-layer B-fragments)
  int*      rowptr = (int*)     (ws + 151900000);    // NN+1 (padded CSR)
  int*      cursor = (int*)     (ws + 152300008);    // NN (real degrees)
  int*      csr    = (int*)     (ws + 152700008);    // ETP_MAX
  float*    dinv   = (float*)   (ws + 163100008);    // NN+1
  int*      bsums  = (int*)     (ws + 163500016);    // NB+1
  int*      rank   = (int*)     (ws + 163501056);    // ET
  uint16_t* w0p    = wpck;                           // elem 0
  uint16_t* w1p    = wpck + 4096;
  uint16_t* w2p    = wpck + 20480;

  constexpr int NB_SCAN = (NN + SCB - 1) / SCB;  // 98

  // ---------------- CSR build (rank pass + atomic-free scatter) ----------------
  hipMemsetAsync(cursor, 0, (size_t)NN * 4, stream);
  rank_kernel<<<(ET + 255) / 256, 256, 0, stream>>>(edst, cursor, rank);
  scan1_kernel<<<NB_SCAN, 256, 0, stream>>>(cursor, rowptr, bsums);
  scan2_kernel<<<1, 256, 0, stream>>>(bsums, NB_SCAN);
  scan3_kernel<<<(NN + 256) / 256, 256, 0, stream>>>(rowptr, bsums, NB_SCAN,
                                                     cursor, dinv, Sb, Tb, csr);
  {
    int nch = (ET + CHUNK - 1) / CHUNK;
    scatter_part_kernel<<<nch * RP, 256, 0, stream>>>(esrc, edst, rowptr, rank, csr);
  }
  // all-layer W pack (independent of CSR; single launch)
  wpack_all_kernel<<<18, 256, 0, stream>>>((const float*)d_in[4], (const float*)d_in[8],
                                           (const float*)d_in[12], wpck);

  // ---------------- GCN: x[n,128] -> gcnHbf[n,32] bf16 ----------------
  {
    int tiles = (NN + 127) / 128;
    if (tiles > 4096) tiles = 4096;
    gemm4b_kernel<128, 16><<<tiles, 256, 0, stream>>>(x, gcn_w, (uint16_t*)bufB, NN);
  }
  gcn_pull_kernel<<<(NN + 15) / 16, 256, 0, stream>>>(rowptr, csr, dinv,
                                                      (const uint16_t*)bufB, gcn_b, gcnHbf);

  // ---------------- GAT g1 (K=16->32, MFMA + fused scores) ----------------
  gemm_mfma_kernel<1, 32><<<NPAD / 64, 256, 0, stream>>>(
      gcnHbf, w0p, (const float*)d_in[5], (const float*)d_in[6], hbf, Sb, Tb, NN);
  fused_gat_kernel<<<(NN * 64 + 255) / 256, 256, 0, stream>>>(
      rowptr, csr, Sb, Tb, hbf, (const float*)d_in[7], bufAb);

  // ---------------- GAT g2 (K=128, MFMA + fused scores) ----------------
  gemm_mfma_kernel<4, 128><<<NPAD / 64, 256, 0, stream>>>(
      bufAb, w1p, (const float*)d_in[9], (const float*)d_in[10], hbf, Sb, Tb, NN);
  fused_gat_kernel<<<(NN * 64 + 255) / 256, 256, 0, stream>>>(
      rowptr, csr, Sb, Tb, hbf, (const float*)d_in[11], bufAb);

  // ---------------- GAT g3 (K=128, MFMA + fused scores) ----------------
  gemm_mfma_kernel<4, 128><<<NPAD / 64, 256, 0, stream>>>(
      bufAb, w2p, (const float*)d_in[13], (const float*)d_in[14], hbf, Sb, Tb, NN);
  fused_gat_kernel<<<(NN * 64 + 255) / 256, 256, 0, stream>>>(
      rowptr, csr, Sb, Tb, hbf, (const float*)d_in[15], bufAb);

  // ---------------- GAT g4 (H=1, C=2, fused gemm+score then attn+pull) --------
  {
    int tiles = (NN + 127) / 128;
    if (tiles > 2048) tiles = 2048;
    gemm_s2_kernel<128, 128><<<tiles, 256, 0, stream>>>(
        bufAb, (const float*)d_in[16], (const float*)d_in[17], (const float*)d_in[18],
        bufB, Sb, Tb, NN);
    fused_gat1_kernel<<<(NN * 16 + 255) / 256, 256, 0, stream>>>(
        rowptr, csr, Sb, Tb, bufB, (const float*)d_in[19], bufC);
  }

  // ---------------- concat + log_softmax -> d_out [HALFN,4] ----------------
  final_kernel<<<(HALFN + 255) / 256, 256, 0, stream>>>(bufC, (float*)d_out);
}